// Round 2
// baseline (273.578 us; speedup 1.0000x reference)
//
#include <hip/hip_runtime.h>
#include <hip/hip_bf16.h>

// B=4, N=2048, C=768, H=16, D=48. FP32 in/out.
// Pipeline: cvt(x,W->bf16) -> gemm_qkv (fused, global_load_lds) -> qkv_reshape
//           -> attn (all-register P, 2-stage software pipeline: QK(t+1) || SM+PV(t))
//           -> gemm_out.
#define B_ 4
#define N_ 2048
#define C_ 768
#define H_ 16
#define D_ 48
#define SCALE_ 0.14433756729740643f
#define LOG2E_ 1.44269504088896f

using bf16 = __hip_bfloat16;
using bf16x8 = __attribute__((ext_vector_type(8))) short;
using f32x4  = __attribute__((ext_vector_type(4))) float;
using f32x16 = __attribute__((ext_vector_type(16))) float;
using u32x2  = __attribute__((ext_vector_type(2))) unsigned int;
using u32x4  = __attribute__((ext_vector_type(4))) unsigned int;

__device__ __forceinline__ unsigned short f2b(float f) {
  bf16 h = __float2bfloat16(f);
  return *reinterpret_cast<unsigned short*>(&h);
}
__device__ __forceinline__ unsigned int pack2(float lo, float hi) {
  return (unsigned int)f2b(lo) | ((unsigned int)f2b(hi) << 16);
}
// packed f32->bf16 (RNE), single instruction
__device__ __forceinline__ unsigned int pk2(float lo, float hi) {
  unsigned int r;
  asm("v_cvt_pk_bf16_f32 %0, %1, %2" : "=v"(r) : "v"(lo), "v"(hi));
  return r;
}
__device__ __forceinline__ uint4 ld8f_cvt(const float* p) {
  float4 a = *reinterpret_cast<const float4*>(p);
  float4 b = *reinterpret_cast<const float4*>(p + 4);
  uint4 u;
  u.x = pack2(a.x, a.y); u.y = pack2(a.z, a.w);
  u.z = pack2(b.x, b.y); u.w = pack2(b.z, b.w);
  return u;
}
// async global->LDS, 16B per lane; LDS dest = l + lane*16B (wave-uniform base)
__device__ __forceinline__ void gload_lds16(const bf16* g, bf16* l) {
  __builtin_amdgcn_global_load_lds(
      (const __attribute__((address_space(1))) unsigned int*)g,
      (__attribute__((address_space(3))) unsigned int*)l, 16, 0, 0);
}

// ---- Kernel 0: fp32 -> bf16 conversions (x, Wq|Wk|Wv stacked, Wo).
__global__ __launch_bounds__(256) void cvt_bf16(
    const float* __restrict__ x,  const float* __restrict__ wq,
    const float* __restrict__ wk, const float* __restrict__ wv,
    const float* __restrict__ wo,
    bf16* __restrict__ xb, bf16* __restrict__ wqkvb, bf16* __restrict__ wob)
{
  const int job = blockIdx.y;
  const float* src; bf16* dst; int n;
  if (job == 0)      { src = x;  dst = xb;              n = B_ * N_ * C_; }
  else if (job == 1) { src = wq; dst = wqkvb;           n = C_ * C_; }
  else if (job == 2) { src = wk; dst = wqkvb + C_ * C_; n = C_ * C_; }
  else if (job == 3) { src = wv; dst = wqkvb + 2 * C_ * C_; n = C_ * C_; }
  else               { src = wo; dst = wob;             n = C_ * C_; }
  const int stride = gridDim.x * 256 * 8;
  for (int i = (blockIdx.x * 256 + threadIdx.x) * 8; i < n; i += stride)
    *(uint4*)(dst + i) = ld8f_cvt(src + i);
}

// ---- Kernel 1: fused QKV GEMM, m97-style. A=xb[8192x768], B=Wqkv[2304x768].
__global__ __launch_bounds__(256) void gemm_qkv(
    const bf16* __restrict__ A, const bf16* __restrict__ Bw,
    const float* __restrict__ bq, const float* __restrict__ bk,
    const float* __restrict__ bv,
    bf16* __restrict__ Q, bf16* __restrict__ K, bf16* __restrict__ V)
{
  __shared__ __align__(16) bf16 As[128 * 64];
  __shared__ __align__(16) bf16 Bs[128 * 64];

  const int tid  = threadIdx.x;
  const int lane = tid & 63, wid = tid >> 6;
  const int wm = (wid >> 1) * 64, wn = (wid & 1) * 64;
  const int row0 = blockIdx.y * 128, col0 = blockIdx.x * 128;
  const int mb = lane & 15, g4 = lane >> 4;
  const int srow = lane >> 3;                    // staging row-in-8
  const int schunk = (lane & 7) ^ (srow & 7);    // swizzled glb k-chunk

  f32x4 acc[4][4];
#pragma unroll
  for (int i = 0; i < 4; ++i)
#pragma unroll
    for (int j = 0; j < 4; ++j) acc[i][j] = (f32x4){0.f, 0.f, 0.f, 0.f};

  for (int k0 = 0; k0 < C_; k0 += 64) {
#pragma unroll
    for (int t = 0; t < 4; ++t) {
      const int rt = wid * 32 + t * 8;
      gload_lds16(A  + (size_t)(row0 + rt + srow) * C_ + k0 + schunk * 8,
                  As + rt * 64);
      gload_lds16(Bw + (size_t)(col0 + rt + srow) * C_ + k0 + schunk * 8,
                  Bs + rt * 64);
    }
    __syncthreads();
#pragma unroll
    for (int ks = 0; ks < 2; ++ks) {
      const int kchunk = ks * 4 + g4;
      bf16x8 af[4], bfr[4];
#pragma unroll
      for (int i = 0; i < 4; ++i) {
        const int row = wm + i * 16 + mb;
        af[i] = *(const bf16x8*)(As + row * 64 + (kchunk ^ (row & 7)) * 8);
      }
#pragma unroll
      for (int j = 0; j < 4; ++j) {
        const int col = wn + j * 16 + mb;
        bfr[j] = *(const bf16x8*)(Bs + col * 64 + (kchunk ^ (col & 7)) * 8);
      }
#pragma unroll
      for (int i = 0; i < 4; ++i)
#pragma unroll
        for (int j = 0; j < 4; ++j)
          acc[i][j] = __builtin_amdgcn_mfma_f32_16x16x32_bf16(af[i], bfr[j], acc[i][j], 0, 0, 0);
    }
    __syncthreads();
  }

  const int z = blockIdx.x / 6;                  // 768/128=6 blocks per proj
  const float* bias = (z == 0) ? bq : (z == 1) ? bk : bv;
  bf16* dst = (z == 0) ? Q : (z == 1) ? K : V;
  const float sc = (z == 0) ? (SCALE_ * LOG2E_) : 1.0f;
  const int crow = g4 * 4;
#pragma unroll
  for (int j = 0; j < 4; ++j) {
    const int oo = col0 - z * 768 + wn + j * 16 + mb;
    const int h = oo / D_, d = oo % D_;
    const float bb = bias[oo];
#pragma unroll
    for (int i = 0; i < 4; ++i) {
#pragma unroll
      for (int reg = 0; reg < 4; ++reg) {
        const int r = row0 + wm + i * 16 + crow + reg;
        const int b_ = r >> 11, n = r & (N_ - 1);
        dst[(((size_t)(b_ * H_ + h)) * N_ + n) * D_ + d] =
            __float2bfloat16((acc[i][j][reg] + bb) * sc);
      }
    }
  }
}

// ---- Kernel 1b: reshape Q,K (in-place) into 32x32 MFMA A/B fragment layout;
// V (from Vtmp) into padded 32x32 A-operand layout Vf[bh][N/16][2][64][8]:
//   element (ksg, dt, l, e) = V[n = ksg*16 + (l>>5)*8 + e][d = dt*32 + (l&31)]
//   dt=1 pad: (l&31)==16 -> 1.0 (fused L row-sum row), (l&31)>16 -> 0.
__global__ __launch_bounds__(256) void qkv_reshape(
    bf16* __restrict__ Q, bf16* __restrict__ K,
    const bf16* __restrict__ Vtmp, bf16* __restrict__ Vf)
{
  __shared__ short T[64 * 50];
  const int bh = blockIdx.x;
  const int t0 = blockIdx.y * 64;
  const int tid = threadIdx.x;
  const size_t base = (size_t)bh * (N_ * D_) + (size_t)t0 * D_;
#pragma unroll 1
  for (int wbuf = 0; wbuf < 2; ++wbuf) {
    bf16* P = (wbuf ? K : Q) + base;
    for (int cc = tid; cc < 384; cc += 256) {
      const int r = cc / 6, ch = cc % 6;
      bf16x8 v8 = *(const bf16x8*)(P + r * D_ + ch * 8);
#pragma unroll
      for (int e = 0; e < 8; ++e) T[r * 50 + ch * 8 + e] = v8[e];
    }
    __syncthreads();
    for (int w = tid; w < 384; w += 256) {
      const int sub = w / 192, rem = w % 192;
      const int kc = rem / 64, rem2 = rem % 64;
      const int g2 = rem2 >> 5, m5 = rem2 & 31;
      bf16x8 o;
#pragma unroll
      for (int e = 0; e < 8; ++e)
        o[e] = T[(sub * 32 + m5) * 50 + kc * 16 + g2 * 8 + e];
      *(bf16x8*)(P + w * 8) = o;
    }
    __syncthreads();
  }
  // V: Vtmp [bh][n][48] -> Vf padded fragment layout
  {
    const bf16* Pv = Vtmp + base;
    for (int cc = tid; cc < 384; cc += 256) {
      const int r = cc / 6, ch = cc % 6;
      bf16x8 v8 = *(const bf16x8*)(Pv + r * D_ + ch * 8);
#pragma unroll
      for (int e = 0; e < 8; ++e) T[r * 50 + ch * 8 + e] = v8[e];
    }
    __syncthreads();
    bf16* W = Vf + (size_t)bh * (N_ * 64) + (size_t)t0 * 64;
    for (int w = tid; w < 512; w += 256) {
      const int ksl = w >> 7;            // 0..3 (K16 group)
      const int dt  = (w >> 6) & 1;      // d-tile
      const int l   = w & 63;
      const int hi = l >> 5, m5 = l & 31;
      bf16x8 o;
      if (dt == 0) {
#pragma unroll
        for (int e = 0; e < 8; ++e)
          o[e] = T[(ksl * 16 + hi * 8 + e) * 50 + m5];
      } else if (m5 < 16) {
#pragma unroll
        for (int e = 0; e < 8; ++e)
          o[e] = T[(ksl * 16 + hi * 8 + e) * 50 + 32 + m5];
      } else {
        const short fill = (m5 == 16) ? (short)0x3F80 : (short)0;
#pragma unroll
        for (int e = 0; e < 8; ++e) o[e] = fill;
      }
      *(bf16x8*)(W + (size_t)(((ksl * 2 + dt) * 64 + l) * 8)) = o;
    }
  }
}

// ---- Kernel 2: zero-LDS register flash attention, 2-stage software pipeline.
// 32-key tiles. Per iteration (2 tiles): QK MFMAs for tile t+1/t+2 are issued
// BEFORE the exp/pack/PV of tiles t/t+1 — MFMA pipe and trans/VALU pipes run
// concurrently within one wave. K frags: depth-2 ping-pong prefetch.
__global__ __launch_bounds__(256) void attn_mfma(
    const bf16* __restrict__ Qf, const bf16* __restrict__ Kf,
    const bf16* __restrict__ Vf, const float* __restrict__ x,
    bf16* __restrict__ Yb)
{
  const int tid  = threadIdx.x;
  const int lane = tid & 63, wid = tid >> 6;
  const int m5 = lane & 31, hi = lane >> 5;
  const int bh = blockIdx.x;
  const int b_ = bh >> 4, h = bh & 15;
  const int q0 = blockIdx.y * 128 + wid * 32;
  const size_t slab  = (size_t)bh * (N_ * D_);
  const size_t slabV = (size_t)bh * (N_ * 64);

  // Q fragments (32 q rows x 48 d)
  bf16x8 qf[3];
  const int kgq = q0 >> 5;
#pragma unroll
  for (int kc = 0; kc < 3; ++kc)
    qf[kc] = *(const bf16x8*)(Qf + slab + (size_t)(((kgq * 3 + kc) * 64) + lane) * 8);

  // hoisted zero accumulator seed (kept live; saves 16 v_mov per QK)
  f32x16 zf;
#pragma unroll
  for (int r = 0; r < 16; ++r) zf[r] = 0.f;

  f32x16 Oacc[2];
#pragma unroll
  for (int dt = 0; dt < 2; ++dt)
#pragma unroll
    for (int r = 0; r < 16; ++r) Oacc[dt][r] = 0.f;

  // per-lane base pointers (tile = 32 keys; K tile stride = 3*512 el, V = 2048 el)
  const bf16* Kp = Kf + slab  + (size_t)lane * 8;
  const bf16* Vp = Vf + slabV + (size_t)lane * 8;

  bf16x8 kf[2][3];
  auto loadK = [&](int t, int p) {
    const bf16* kp = Kp + (size_t)t * (3 * 512);
#pragma unroll
    for (int kc = 0; kc < 3; ++kc)
      kf[p][kc] = *(const bf16x8*)(kp + kc * 512);
  };
  auto vload = [&](int t, bf16x8 (&vA)[2][2]) {
    const bf16* vp = Vp + (size_t)t * 2048;
#pragma unroll
    for (int ks = 0; ks < 2; ++ks)
#pragma unroll
      for (int dt = 0; dt < 2; ++dt)
        vA[ks][dt] = *(const bf16x8*)(vp + (ks * 2 + dt) * 512);
  };
  auto qk = [&](int p, f32x16& dst) {
    dst = __builtin_amdgcn_mfma_f32_32x32x16_bf16(kf[p][0], qf[0], zf, 0, 0, 0);
    dst = __builtin_amdgcn_mfma_f32_32x32x16_bf16(kf[p][1], qf[1], dst, 0, 0, 0);
    dst = __builtin_amdgcn_mfma_f32_32x32x16_bf16(kf[p][2], qf[2], dst, 0, 0, 0);
  };
  // exp -> pack(bf16 B-frag via cvt_pk+permlane32_swap) -> PV (+fused L row)
  auto smpv = [&](f32x16& S, bf16x8 (&vA)[2][2]) {
#pragma unroll
    for (int r = 0; r < 16; ++r)
      S[r] = __builtin_amdgcn_exp2f(S[r]);
#pragma unroll
    for (int ks = 0; ks < 2; ++ks) {
      const int qa = ks * 2;
      const unsigned A0 = pk2(S[4 * qa + 0], S[4 * qa + 1]);
      const unsigned A1 = pk2(S[4 * qa + 2], S[4 * qa + 3]);
      const unsigned B0 = pk2(S[4 * qa + 4], S[4 * qa + 5]);
      const unsigned B1 = pk2(S[4 * qa + 6], S[4 * qa + 7]);
      const u32x2 r02 = __builtin_amdgcn_permlane32_swap(A0, B0, false, false);
      const u32x2 r13 = __builtin_amdgcn_permlane32_swap(A1, B1, false, false);
      u32x4 pw;
      pw.x = r02.x; pw.y = r13.x; pw.z = r02.y; pw.w = r13.y;
      const bf16x8 pb = (bf16x8)pw;
      Oacc[0] = __builtin_amdgcn_mfma_f32_32x32x16_bf16(vA[ks][0], pb, Oacc[0], 0, 0, 0);
      Oacc[1] = __builtin_amdgcn_mfma_f32_32x32x16_bf16(vA[ks][1], pb, Oacc[1], 0, 0, 0);
    }
  };

  // ---- pipeline: prologue
  f32x16 stA, stB;
  bf16x8 vA0[2][2], vA1[2][2];
  loadK(0, 0);
  loadK(1, 1);
  qk(0, stA);                 // tile 0 (one-time cold-load stall)
  loadK(2, 0);

  // 64 tiles of 32 keys; 2 tiles per iteration. Tiles >=64 are issued but
  // their results are never consumed (reads land in the adjacent ws buffer).
#pragma unroll 1
  for (int it = 0; it < 32; ++it) {
    const int t = it * 2;
    vload(t, vA0);
    qk(1, stB);               // QK tile t+1 (kf[1] loaded a full iter ago)
    loadK(t + 3, 1);
    smpv(stA, vA0);           // exp/pack/PV tile t (covers kf/vA latency)
    vload(t + 1, vA1);
    qk(0, stA);               // QK tile t+2
    loadK(t + 4, 0);
    smpv(stB, vA1);           // exp/pack/PV tile t+1
  }

  // L[q] lives in Oacc[1] row 16 = reg 8 of hi=0 lanes; broadcast to hi=1.
  const float lf = Oacc[1][8];
  const unsigned lu = __builtin_bit_cast(unsigned, lf);
  const u32x2 lsw = __builtin_amdgcn_permlane32_swap(lu, lu, false, false);
  const float Lv = __builtin_bit_cast(float, lsw.x);
  const float inv = 1.f / Lv;

  const int n = q0 + m5;
  const size_t rowoff = ((size_t)(b_ * N_ + n)) * C_ + h * D_;
#pragma unroll
  for (int qq = 0; qq < 4; ++qq) {
    const size_t off = rowoff + 8 * qq + 4 * hi;      // d = 8qq+4hi .. +3
    const float4 xr = *(const float4*)(x + off);
    u32x2 wv;
    wv.x = pk2(Oacc[0][4 * qq + 0] * inv + xr.x, Oacc[0][4 * qq + 1] * inv + xr.y);
    wv.y = pk2(Oacc[0][4 * qq + 2] * inv + xr.z, Oacc[0][4 * qq + 3] * inv + xr.w);
    *(u32x2*)(Yb + off) = wv;
  }
#pragma unroll
  for (int qq = 0; qq < 2; ++qq) {
    const size_t off = rowoff + 32 + 8 * qq + 4 * hi; // d = 32+8qq+4hi .. +3
    const float4 xr = *(const float4*)(x + off);
    u32x2 wv;
    wv.x = pk2(Oacc[1][4 * qq + 0] * inv + xr.x, Oacc[1][4 * qq + 1] * inv + xr.y);
    wv.y = pk2(Oacc[1][4 * qq + 2] * inv + xr.z, Oacc[1][4 * qq + 3] * inv + xr.w);
    *(u32x2*)(Yb + off) = wv;
  }
}

// ---- Kernel 3: O projection + residuals, m97-style staging.
// out[r][o] = acc + bo[o] + float(Yb[r][o]) + x[r][o]
__global__ __launch_bounds__(256) void gemm_out(
    const bf16* __restrict__ Yb, const bf16* __restrict__ Bw,
    const float* __restrict__ bo, const float* __restrict__ x,
    float* __restrict__ out)
{
  __shared__ __align__(16) bf16 As[128 * 64];
  __shared__ __align__(16) bf16 Bs[128 * 64];

  const int tid  = threadIdx.x;
  const int lane = tid & 63, wid = tid >> 6;
  const int wm = (wid >> 1) * 64, wn = (wid & 1) * 64;
  const int row0 = blockIdx.y * 128, col0 = blockIdx.x * 128;
  const int mb = lane & 15, g4 = lane >> 4;
  const int srow = lane >> 3;
  const int schunk = (lane & 7) ^ (srow & 7);

  f32x4 acc[4][4];
#pragma unroll
  for (int i = 0; i < 4; ++i)
#pragma unroll
    for (int j = 0; j < 4; ++j) acc[i][j] = (f32x4){0.f, 0.f, 0.f, 0.f};

  for (int k0 = 0; k0 < C_; k0 += 64) {
#pragma unroll
    for (int t = 0; t < 4; ++t) {
      const int rt = wid * 32 + t * 8;
      gload_lds16(Yb + (size_t)(row0 + rt + srow) * C_ + k0 + schunk * 8,
                  As + rt * 64);
      gload_lds16(Bw + (size_t)(col0 + rt + srow) * C_ + k0 + schunk * 8,
                  Bs + rt * 64);
    }
    __syncthreads();
#pragma unroll
    for (int ks = 0; ks < 2; ++ks) {
      const int kchunk = ks * 4 + g4;
      bf16x8 af[4], bfr[4];
#pragma unroll
      for (int i = 0; i < 4; ++i) {
        const int row = wm + i * 16 + mb;
        af[i] = *(const bf16x8*)(As + row * 64 + (kchunk ^ (row & 7)) * 8);
      }
#pragma unroll
      for (int j = 0; j < 4; ++j) {
        const int col = wn + j * 16 + mb;
        bfr[j] = *(const bf16x8*)(Bs + col * 64 + (kchunk ^ (col & 7)) * 8);
      }
#pragma unroll
      for (int i = 0; i < 4; ++i)
#pragma unroll
        for (int j = 0; j < 4; ++j)
          acc[i][j] = __builtin_amdgcn_mfma_f32_16x16x32_bf16(af[i], bfr[j], acc[i][j], 0, 0, 0);
    }
    __syncthreads();
  }

  const int crow = g4 * 4;
#pragma unroll
  for (int j = 0; j < 4; ++j) {
    const int o = col0 + wn + j * 16 + mb;
    const float bb = bo[o];
#pragma unroll
    for (int i = 0; i < 4; ++i) {
#pragma unroll
      for (int reg = 0; reg < 4; ++reg) {
        const int r = row0 + wm + i * 16 + crow + reg;
        const size_t off = (size_t)r * C_ + o;
        out[off] = acc[i][j][reg] + bb + __bfloat162float(Yb[off]) + x[off];
      }
    }
  }
}

extern "C" void kernel_launch(void* const* d_in, const int* in_sizes, int n_in,
                              void* d_out, int out_size, void* d_ws, size_t ws_size,
                              hipStream_t stream)
{
  const float* x  = (const float*)d_in[0];
  const float* wq = (const float*)d_in[1];
  const float* bq = (const float*)d_in[2];
  const float* wk = (const float*)d_in[3];
  const float* bk = (const float*)d_in[4];
  const float* wv = (const float*)d_in[5];
  const float* bv = (const float*)d_in[6];
  const float* wo = (const float*)d_in[7];
  const float* bo = (const float*)d_in[8];
  float* out = (float*)d_out;

  const size_t nEl  = (size_t)B_ * N_ * C_;     // 6,291,456
  const size_t wEl  = (size_t)C_ * C_;          // 589,824
  const size_t vfEl = (size_t)B_ * H_ * N_ * 64; // 8,388,608 (padded V frags)
  bf16* Q     = (bf16*)d_ws;                    // fragment layout after reshape
  bf16* K     = Q + nEl;
  bf16* Vf    = K + nEl;                        // padded V A-fragment layout
  bf16* Yb    = Vf + vfEl;                      // Vtmp before attn; then y=attn+x
  bf16* xb    = Yb + nEl;                       // [8192][768] bf16
  bf16* wqkvb = xb + nEl;                       // [2304][768] bf16 stacked
  bf16* wob   = wqkvb + 3 * wEl;                // [768][768] bf16

  dim3 gcvt(768, 5);
  cvt_bf16<<<gcvt, dim3(256), 0, stream>>>(x, wq, wk, wv, wo, xb, wqkvb, wob);

  dim3 gqkv(18, 64);                            // 2304/128 x 8192/128
  gemm_qkv<<<gqkv, dim3(256), 0, stream>>>(xb, wqkvb, bq, bk, bv, Q, K, Yb);

  dim3 grs(B_ * H_, N_ / 64);                   // Q,K in-place; V: Yb -> Vf
  qkv_reshape<<<grs, dim3(256), 0, stream>>>(Q, K, Yb, Vf);

  dim3 gattn(B_ * H_, N_ / 128);                // (64, 16)
  attn_mfma<<<gattn, dim3(256), 0, stream>>>(Q, K, Vf, x, Yb);

  dim3 gout(6, 64);                             // 768/128 x 8192/128
  gemm_out<<<gout, dim3(256), 0, stream>>>(Yb, wob, bo, x, out);
}

// Round 3
// 261.676 us; speedup vs baseline: 1.0455x; 1.0455x over previous
//
#include <hip/hip_runtime.h>
#include <hip/hip_bf16.h>

// B=4, N=2048, C=768, H=16, D=48. FP32 in/out.
// Pipeline: cvt(x,W->bf16) -> gemm_qkv (fused, global_load_lds) -> qkv_reshape
//           -> attn (LDS-staged K/V shared by 4 waves, double-buffered
//              global_load_lds prefetch; all-register P via cvt_pk+permlane)
//           -> gemm_out.
#define B_ 4
#define N_ 2048
#define C_ 768
#define H_ 16
#define D_ 48
#define SCALE_ 0.14433756729740643f
#define LOG2E_ 1.44269504088896f

using bf16 = __hip_bfloat16;
using bf16x8 = __attribute__((ext_vector_type(8))) short;
using f32x4  = __attribute__((ext_vector_type(4))) float;
using f32x16 = __attribute__((ext_vector_type(16))) float;
using u32x2  = __attribute__((ext_vector_type(2))) unsigned int;
using u32x4  = __attribute__((ext_vector_type(4))) unsigned int;

__device__ __forceinline__ unsigned short f2b(float f) {
  bf16 h = __float2bfloat16(f);
  return *reinterpret_cast<unsigned short*>(&h);
}
__device__ __forceinline__ unsigned int pack2(float lo, float hi) {
  return (unsigned int)f2b(lo) | ((unsigned int)f2b(hi) << 16);
}
// packed f32->bf16 (RNE), single instruction
__device__ __forceinline__ unsigned int pk2(float lo, float hi) {
  unsigned int r;
  asm("v_cvt_pk_bf16_f32 %0, %1, %2" : "=v"(r) : "v"(lo), "v"(hi));
  return r;
}
__device__ __forceinline__ uint4 ld8f_cvt(const float* p) {
  float4 a = *reinterpret_cast<const float4*>(p);
  float4 b = *reinterpret_cast<const float4*>(p + 4);
  uint4 u;
  u.x = pack2(a.x, a.y); u.y = pack2(a.z, a.w);
  u.z = pack2(b.x, b.y); u.w = pack2(b.z, b.w);
  return u;
}
// async global->LDS, 16B per lane; LDS dest = wave-uniform base + lane*16B
__device__ __forceinline__ void gload_lds16(const bf16* g, bf16* l) {
  __builtin_amdgcn_global_load_lds(
      (const __attribute__((address_space(1))) unsigned int*)g,
      (__attribute__((address_space(3))) unsigned int*)l, 16, 0, 0);
}

// ---- Kernel 0: fp32 -> bf16 conversions (x, Wq|Wk|Wv stacked, Wo).
__global__ __launch_bounds__(256) void cvt_bf16(
    const float* __restrict__ x,  const float* __restrict__ wq,
    const float* __restrict__ wk, const float* __restrict__ wv,
    const float* __restrict__ wo,
    bf16* __restrict__ xb, bf16* __restrict__ wqkvb, bf16* __restrict__ wob)
{
  const int job = blockIdx.y;
  const float* src; bf16* dst; int n;
  if (job == 0)      { src = x;  dst = xb;              n = B_ * N_ * C_; }
  else if (job == 1) { src = wq; dst = wqkvb;           n = C_ * C_; }
  else if (job == 2) { src = wk; dst = wqkvb + C_ * C_; n = C_ * C_; }
  else if (job == 3) { src = wv; dst = wqkvb + 2 * C_ * C_; n = C_ * C_; }
  else               { src = wo; dst = wob;             n = C_ * C_; }
  const int stride = gridDim.x * 256 * 8;
  for (int i = (blockIdx.x * 256 + threadIdx.x) * 8; i < n; i += stride)
    *(uint4*)(dst + i) = ld8f_cvt(src + i);
}

// ---- Kernel 1: fused QKV GEMM, m97-style. A=xb[8192x768], B=Wqkv[2304x768].
__global__ __launch_bounds__(256) void gemm_qkv(
    const bf16* __restrict__ A, const bf16* __restrict__ Bw,
    const float* __restrict__ bq, const float* __restrict__ bk,
    const float* __restrict__ bv,
    bf16* __restrict__ Q, bf16* __restrict__ K, bf16* __restrict__ V)
{
  __shared__ __align__(16) bf16 As[128 * 64];
  __shared__ __align__(16) bf16 Bs[128 * 64];

  const int tid  = threadIdx.x;
  const int lane = tid & 63, wid = tid >> 6;
  const int wm = (wid >> 1) * 64, wn = (wid & 1) * 64;
  const int row0 = blockIdx.y * 128, col0 = blockIdx.x * 128;
  const int mb = lane & 15, g4 = lane >> 4;
  const int srow = lane >> 3;                    // staging row-in-8
  const int schunk = (lane & 7) ^ (srow & 7);    // swizzled glb k-chunk

  f32x4 acc[4][4];
#pragma unroll
  for (int i = 0; i < 4; ++i)
#pragma unroll
    for (int j = 0; j < 4; ++j) acc[i][j] = (f32x4){0.f, 0.f, 0.f, 0.f};

  for (int k0 = 0; k0 < C_; k0 += 64) {
#pragma unroll
    for (int t = 0; t < 4; ++t) {
      const int rt = wid * 32 + t * 8;
      gload_lds16(A  + (size_t)(row0 + rt + srow) * C_ + k0 + schunk * 8,
                  As + rt * 64);
      gload_lds16(Bw + (size_t)(col0 + rt + srow) * C_ + k0 + schunk * 8,
                  Bs + rt * 64);
    }
    __syncthreads();
#pragma unroll
    for (int ks = 0; ks < 2; ++ks) {
      const int kchunk = ks * 4 + g4;
      bf16x8 af[4], bfr[4];
#pragma unroll
      for (int i = 0; i < 4; ++i) {
        const int row = wm + i * 16 + mb;
        af[i] = *(const bf16x8*)(As + row * 64 + (kchunk ^ (row & 7)) * 8);
      }
#pragma unroll
      for (int j = 0; j < 4; ++j) {
        const int col = wn + j * 16 + mb;
        bfr[j] = *(const bf16x8*)(Bs + col * 64 + (kchunk ^ (col & 7)) * 8);
      }
#pragma unroll
      for (int i = 0; i < 4; ++i)
#pragma unroll
        for (int j = 0; j < 4; ++j)
          acc[i][j] = __builtin_amdgcn_mfma_f32_16x16x32_bf16(af[i], bfr[j], acc[i][j], 0, 0, 0);
    }
    __syncthreads();
  }

  const int z = blockIdx.x / 6;                  // 768/128=6 blocks per proj
  const float* bias = (z == 0) ? bq : (z == 1) ? bk : bv;
  bf16* dst = (z == 0) ? Q : (z == 1) ? K : V;
  const float sc = (z == 0) ? (SCALE_ * LOG2E_) : 1.0f;
  const int crow = g4 * 4;
#pragma unroll
  for (int j = 0; j < 4; ++j) {
    const int oo = col0 - z * 768 + wn + j * 16 + mb;
    const int h = oo / D_, d = oo % D_;
    const float bb = bias[oo];
#pragma unroll
    for (int i = 0; i < 4; ++i) {
#pragma unroll
      for (int reg = 0; reg < 4; ++reg) {
        const int r = row0 + wm + i * 16 + crow + reg;
        const int b_ = r >> 11, n = r & (N_ - 1);
        dst[(((size_t)(b_ * H_ + h)) * N_ + n) * D_ + d] =
            __float2bfloat16((acc[i][j][reg] + bb) * sc);
      }
    }
  }
}

// ---- Kernel 1b: reshape Q,K (in-place) into 32x32 MFMA A/B fragment layout;
// V (from Vtmp) into padded 32x32 A-operand layout Vf[bh][N/16][2][64][8]:
//   element (ksg, dt, l, e) = V[n = ksg*16 + (l>>5)*8 + e][d = dt*32 + (l&31)]
//   dt=1 pad: (l&31)==16 -> 1.0 (fused L row-sum row), (l&31)>16 -> 0.
__global__ __launch_bounds__(256) void qkv_reshape(
    bf16* __restrict__ Q, bf16* __restrict__ K,
    const bf16* __restrict__ Vtmp, bf16* __restrict__ Vf)
{
  __shared__ short T[64 * 50];
  const int bh = blockIdx.x;
  const int t0 = blockIdx.y * 64;
  const int tid = threadIdx.x;
  const size_t base = (size_t)bh * (N_ * D_) + (size_t)t0 * D_;
#pragma unroll 1
  for (int wbuf = 0; wbuf < 2; ++wbuf) {
    bf16* P = (wbuf ? K : Q) + base;
    for (int cc = tid; cc < 384; cc += 256) {
      const int r = cc / 6, ch = cc % 6;
      bf16x8 v8 = *(const bf16x8*)(P + r * D_ + ch * 8);
#pragma unroll
      for (int e = 0; e < 8; ++e) T[r * 50 + ch * 8 + e] = v8[e];
    }
    __syncthreads();
    for (int w = tid; w < 384; w += 256) {
      const int sub = w / 192, rem = w % 192;
      const int kc = rem / 64, rem2 = rem % 64;
      const int g2 = rem2 >> 5, m5 = rem2 & 31;
      bf16x8 o;
#pragma unroll
      for (int e = 0; e < 8; ++e)
        o[e] = T[(sub * 32 + m5) * 50 + kc * 16 + g2 * 8 + e];
      *(bf16x8*)(P + w * 8) = o;
    }
    __syncthreads();
  }
  // V: Vtmp [bh][n][48] -> Vf padded fragment layout
  {
    const bf16* Pv = Vtmp + base;
    for (int cc = tid; cc < 384; cc += 256) {
      const int r = cc / 6, ch = cc % 6;
      bf16x8 v8 = *(const bf16x8*)(Pv + r * D_ + ch * 8);
#pragma unroll
      for (int e = 0; e < 8; ++e) T[r * 50 + ch * 8 + e] = v8[e];
    }
    __syncthreads();
    bf16* W = Vf + (size_t)bh * (N_ * 64) + (size_t)t0 * 64;
    for (int w = tid; w < 512; w += 256) {
      const int ksl = w >> 7;            // 0..3 (K16 group)
      const int dt  = (w >> 6) & 1;      // d-tile
      const int l   = w & 63;
      const int hi = l >> 5, m5 = l & 31;
      bf16x8 o;
      if (dt == 0) {
#pragma unroll
        for (int e = 0; e < 8; ++e)
          o[e] = T[(ksl * 16 + hi * 8 + e) * 50 + m5];
      } else if (m5 < 16) {
#pragma unroll
        for (int e = 0; e < 8; ++e)
          o[e] = T[(ksl * 16 + hi * 8 + e) * 50 + 32 + m5];
      } else {
        const short fill = (m5 == 16) ? (short)0x3F80 : (short)0;
#pragma unroll
        for (int e = 0; e < 8; ++e) o[e] = fill;
      }
      *(bf16x8*)(W + (size_t)(((ksl * 2 + dt) * 64 + l) * 8)) = o;
    }
  }
}

// ---- Kernel 2: LDS-staged register flash attention.
// 4 waves/block share one bh slab: K/V tiles (64 keys = 14 x 1KB chunks) are
// staged ONCE per block via global_load_lds (double-buffered, prefetch
// distance 1 tile), then each wave ds_reads its fragments. 4x L2/L3 dedup +
// block-level latency hiding the compiler can't re-serialize away.
__global__ __launch_bounds__(256, 4) void attn_mfma(
    const bf16* __restrict__ Qf, const bf16* __restrict__ Kf,
    const bf16* __restrict__ Vf, const float* __restrict__ x,
    bf16* __restrict__ Yb)
{
  __shared__ __align__(16) bf16 Ls[2 * 7168];    // 2 bufs x (6KB K + 8KB V)

  const int tid  = threadIdx.x;
  const int lane = tid & 63, wid = tid >> 6;
  const int m5 = lane & 31, hi = lane >> 5;
  const int bh = blockIdx.x;
  const int b_ = bh >> 4, h = bh & 15;
  const int q0 = blockIdx.y * 128 + wid * 32;
  const size_t slab  = (size_t)bh * (N_ * D_);
  const size_t slabV = (size_t)bh * (N_ * 64);

  // Q fragments (32 q rows x 48 d), live whole kernel
  bf16x8 qf[3];
  const int kgq = q0 >> 5;
#pragma unroll
  for (int kc = 0; kc < 3; ++kc)
    qf[kc] = *(const bf16x8*)(Qf + slab + (size_t)(((kgq * 3 + kc) * 64) + lane) * 8);

  f32x16 zf;
#pragma unroll
  for (int r = 0; r < 16; ++r) zf[r] = 0.f;

  f32x16 Oacc[2];
#pragma unroll
  for (int dt = 0; dt < 2; ++dt)
#pragma unroll
    for (int r = 0; r < 16; ++r) Oacc[dt][r] = 0.f;

  // stage tile t (64 keys) into buffer buf: chunks 0-5 = K (6KB), 6-13 = V (8KB)
  const bf16* kb = Kf + slab  + (size_t)lane * 8;
  const bf16* vb = Vf + slabV + (size_t)lane * 8;
  auto stage = [&](int t, int buf) {
    bf16* dstb = Ls + buf * 7168;
    const bf16* kt = kb + (size_t)t * 3072;
    const bf16* vt = vb + (size_t)t * 4096;
    for (int c = wid; c < 14; c += 4) {
      if (c < 6) gload_lds16(kt + c * 512, dstb + c * 512);
      else       gload_lds16(vt + (c - 6) * 512, dstb + c * 512);
    }
  };

  // compute one 32-key sub-tile from LDS buffer buf
  auto sub = [&](int buf, int s) {
    const bf16* Lb = Ls + buf * 7168 + (size_t)lane * 8;
    bf16x8 kf[3], vA[2][2];
#pragma unroll
    for (int kc = 0; kc < 3; ++kc)
      kf[kc] = *(const bf16x8*)(Lb + (s * 3 + kc) * 512);
#pragma unroll
    for (int ks = 0; ks < 2; ++ks)
#pragma unroll
      for (int dt = 0; dt < 2; ++dt)
        vA[ks][dt] = *(const bf16x8*)(Lb + (6 + s * 4 + ks * 2 + dt) * 512);
    f32x16 S;
    S = __builtin_amdgcn_mfma_f32_32x32x16_bf16(kf[0], qf[0], zf, 0, 0, 0);
    S = __builtin_amdgcn_mfma_f32_32x32x16_bf16(kf[1], qf[1], S, 0, 0, 0);
    S = __builtin_amdgcn_mfma_f32_32x32x16_bf16(kf[2], qf[2], S, 0, 0, 0);
#pragma unroll
    for (int r = 0; r < 16; ++r)
      S[r] = __builtin_amdgcn_exp2f(S[r]);
    // S reg 4*qq+rr = P[q=lane&31][k32 = rr + 8*qq + 4*hi]
#pragma unroll
    for (int ks = 0; ks < 2; ++ks) {
      const int qa = ks * 2;
      const unsigned A0 = pk2(S[4 * qa + 0], S[4 * qa + 1]);
      const unsigned A1 = pk2(S[4 * qa + 2], S[4 * qa + 3]);
      const unsigned B0 = pk2(S[4 * qa + 4], S[4 * qa + 5]);
      const unsigned B1 = pk2(S[4 * qa + 6], S[4 * qa + 7]);
      const u32x2 r02 = __builtin_amdgcn_permlane32_swap(A0, B0, false, false);
      const u32x2 r13 = __builtin_amdgcn_permlane32_swap(A1, B1, false, false);
      u32x4 pw;
      pw.x = r02.x; pw.y = r13.x; pw.z = r02.y; pw.w = r13.y;
      const bf16x8 pb = (bf16x8)pw;
      Oacc[0] = __builtin_amdgcn_mfma_f32_32x32x16_bf16(vA[ks][0], pb, Oacc[0], 0, 0, 0);
      Oacc[1] = __builtin_amdgcn_mfma_f32_32x32x16_bf16(vA[ks][1], pb, Oacc[1], 0, 0, 0);
    }
  };

  stage(0, 0);
  __syncthreads();
  int buf = 0;
#pragma unroll 1
  for (int t = 0; t < 32; ++t) {
    if (t + 1 < 32) stage(t + 1, buf ^ 1);     // prefetch next tile first
    sub(buf, 0);
    sub(buf, 1);
    __syncthreads();                           // drains vmcnt: next buf ready
    buf ^= 1;
  }

  // L[q] lives in Oacc[1] row 16 = reg 8 of hi=0 lanes; broadcast to hi=1.
  const float lf = Oacc[1][8];
  const unsigned lu = __builtin_bit_cast(unsigned, lf);
  const u32x2 lsw = __builtin_amdgcn_permlane32_swap(lu, lu, false, false);
  const float Lv = __builtin_bit_cast(float, lsw.x);
  const float inv = 1.f / Lv;

  const int n = q0 + m5;
  const size_t rowoff = ((size_t)(b_ * N_ + n)) * C_ + h * D_;
#pragma unroll
  for (int qq = 0; qq < 4; ++qq) {
    const size_t off = rowoff + 8 * qq + 4 * hi;      // d = 8qq+4hi .. +3
    const float4 xr = *(const float4*)(x + off);
    u32x2 wv;
    wv.x = pk2(Oacc[0][4 * qq + 0] * inv + xr.x, Oacc[0][4 * qq + 1] * inv + xr.y);
    wv.y = pk2(Oacc[0][4 * qq + 2] * inv + xr.z, Oacc[0][4 * qq + 3] * inv + xr.w);
    *(u32x2*)(Yb + off) = wv;
  }
#pragma unroll
  for (int qq = 0; qq < 2; ++qq) {
    const size_t off = rowoff + 32 + 8 * qq + 4 * hi; // d = 32+8qq+4hi .. +3
    const float4 xr = *(const float4*)(x + off);
    u32x2 wv;
    wv.x = pk2(Oacc[1][4 * qq + 0] * inv + xr.x, Oacc[1][4 * qq + 1] * inv + xr.y);
    wv.y = pk2(Oacc[1][4 * qq + 2] * inv + xr.z, Oacc[1][4 * qq + 3] * inv + xr.w);
    *(u32x2*)(Yb + off) = wv;
  }
}

// ---- Kernel 3: O projection + residuals, m97-style staging.
// out[r][o] = acc + bo[o] + float(Yb[r][o]) + x[r][o]
__global__ __launch_bounds__(256) void gemm_out(
    const bf16* __restrict__ Yb, const bf16* __restrict__ Bw,
    const float* __restrict__ bo, const float* __restrict__ x,
    float* __restrict__ out)
{
  __shared__ __align__(16) bf16 As[128 * 64];
  __shared__ __align__(16) bf16 Bs[128 * 64];

  const int tid  = threadIdx.x;
  const int lane = tid & 63, wid = tid >> 6;
  const int wm = (wid >> 1) * 64, wn = (wid & 1) * 64;
  const int row0 = blockIdx.y * 128, col0 = blockIdx.x * 128;
  const int mb = lane & 15, g4 = lane >> 4;
  const int srow = lane >> 3;
  const int schunk = (lane & 7) ^ (srow & 7);

  f32x4 acc[4][4];
#pragma unroll
  for (int i = 0; i < 4; ++i)
#pragma unroll
    for (int j = 0; j < 4; ++j) acc[i][j] = (f32x4){0.f, 0.f, 0.f, 0.f};

  for (int k0 = 0; k0 < C_; k0 += 64) {
#pragma unroll
    for (int t = 0; t < 4; ++t) {
      const int rt = wid * 32 + t * 8;
      gload_lds16(Yb + (size_t)(row0 + rt + srow) * C_ + k0 + schunk * 8,
                  As + rt * 64);
      gload_lds16(Bw + (size_t)(col0 + rt + srow) * C_ + k0 + schunk * 8,
                  Bs + rt * 64);
    }
    __syncthreads();
#pragma unroll
    for (int ks = 0; ks < 2; ++ks) {
      const int kchunk = ks * 4 + g4;
      bf16x8 af[4], bfr[4];
#pragma unroll
      for (int i = 0; i < 4; ++i) {
        const int row = wm + i * 16 + mb;
        af[i] = *(const bf16x8*)(As + row * 64 + (kchunk ^ (row & 7)) * 8);
      }
#pragma unroll
      for (int j = 0; j < 4; ++j) {
        const int col = wn + j * 16 + mb;
        bfr[j] = *(const bf16x8*)(Bs + col * 64 + (kchunk ^ (col & 7)) * 8);
      }
#pragma unroll
      for (int i = 0; i < 4; ++i)
#pragma unroll
        for (int j = 0; j < 4; ++j)
          acc[i][j] = __builtin_amdgcn_mfma_f32_16x16x32_bf16(af[i], bfr[j], acc[i][j], 0, 0, 0);
    }
    __syncthreads();
  }

  const int crow = g4 * 4;
#pragma unroll
  for (int j = 0; j < 4; ++j) {
    const int o = col0 + wn + j * 16 + mb;
    const float bb = bo[o];
#pragma unroll
    for (int i = 0; i < 4; ++i) {
#pragma unroll
      for (int reg = 0; reg < 4; ++reg) {
        const int r = row0 + wm + i * 16 + crow + reg;
        const size_t off = (size_t)r * C_ + o;
        out[off] = acc[i][j][reg] + bb + __bfloat162float(Yb[off]) + x[off];
      }
    }
  }
}

extern "C" void kernel_launch(void* const* d_in, const int* in_sizes, int n_in,
                              void* d_out, int out_size, void* d_ws, size_t ws_size,
                              hipStream_t stream)
{
  const float* x  = (const float*)d_in[0];
  const float* wq = (const float*)d_in[1];
  const float* bq = (const float*)d_in[2];
  const float* wk = (const float*)d_in[3];
  const float* bk = (const float*)d_in[4];
  const float* wv = (const float*)d_in[5];
  const float* bv = (const float*)d_in[6];
  const float* wo = (const float*)d_in[7];
  const float* bo = (const float*)d_in[8];
  float* out = (float*)d_out;

  const size_t nEl  = (size_t)B_ * N_ * C_;     // 6,291,456
  const size_t wEl  = (size_t)C_ * C_;          // 589,824
  const size_t vfEl = (size_t)B_ * H_ * N_ * 64; // 8,388,608 (padded V frags)
  bf16* Q     = (bf16*)d_ws;                    // fragment layout after reshape
  bf16* K     = Q + nEl;
  bf16* Vf    = K + nEl;                        // padded V A-fragment layout
  bf16* Yb    = Vf + vfEl;                      // Vtmp before attn; then y=attn+x
  bf16* xb    = Yb + nEl;                       // [8192][768] bf16
  bf16* wqkvb = xb + nEl;                       // [2304][768] bf16 stacked
  bf16* wob   = wqkvb + 3 * wEl;                // [768][768] bf16

  dim3 gcvt(768, 5);
  cvt_bf16<<<gcvt, dim3(256), 0, stream>>>(x, wq, wk, wv, wo, xb, wqkvb, wob);

  dim3 gqkv(18, 64);                            // 2304/128 x 8192/128
  gemm_qkv<<<gqkv, dim3(256), 0, stream>>>(xb, wqkvb, bq, bk, bv, Q, K, Yb);

  dim3 grs(B_ * H_, N_ / 64);                   // Q,K in-place; V: Yb -> Vf
  qkv_reshape<<<grs, dim3(256), 0, stream>>>(Q, K, Yb, Vf);

  dim3 gattn(B_ * H_, N_ / 128);                // (64, 16)
  attn_mfma<<<gattn, dim3(256), 0, stream>>>(Q, K, Vf, x, Yb);

  dim3 gout(6, 64);                             // 768/128 x 8192/128
  gemm_out<<<gout, dim3(256), 0, stream>>>(Yb, wob, bo, x, out);
}